// Round 4
// baseline (1826.487 us; speedup 1.0000x reference)
//
#include <hip/hip_runtime.h>

typedef unsigned short u16;
typedef unsigned long long u64;
typedef __attribute__((ext_vector_type(8))) short bf16x8;
typedef __attribute__((ext_vector_type(4))) float f32x4;
typedef __attribute__((ext_vector_type(4))) unsigned short us4;

#define MFMA(a,b,c) __builtin_amdgcn_mfma_f32_16x16x32_bf16((a),(b),(c),0,0,0)
#define KEEP(x) asm volatile("" : "+v"(x))

// B=128, SEQ=200, VOCAB=1400 (pad 1408), D=H=256, 4H=1024, NCLS=128, M=B*SEQ=25600

static __device__ __forceinline__ u16 f2b(float f){
  unsigned u = __float_as_uint(f);
  u += 0x7fffu + ((u >> 16) & 1u);          // RNE fp32 -> bf16
  return (u16)(u >> 16);
}
static __device__ __forceinline__ float b2f(u16 v){
  return __uint_as_float(((unsigned)v) << 16);
}
static __device__ __forceinline__ float sigm(float x){ return 1.0f/(1.0f+__expf(-x)); }
static __device__ __forceinline__ float tanhx(float x){
  x = fminf(fmaxf(x, -15.f), 15.f);
  float e = __expf(-2.f*x);
  return (1.f - e)/(1.f + e);
}
static __device__ __forceinline__ void gl16(const void* g, void* l){
  __builtin_amdgcn_global_load_lds((const __attribute__((address_space(1))) void*)g,
                                   (__attribute__((address_space(3))) void*)l, 16, 0, 0);
}

// ---------------- fused prep: inputs cvt + emb transpose-cvt + weights ----
__global__ __launch_bounds__(256) void k_prep(
  const float* __restrict__ in0, u16* __restrict__ A0,
  const float* __restrict__ emb, u16* __restrict__ embT,
  const float* __restrict__ s0, const float* __restrict__ s1, const float* __restrict__ s2,
  const float* __restrict__ s3, const float* __restrict__ s4, const float* __restrict__ s5,
  const float* __restrict__ s6,
  u16* __restrict__ d0, u16* __restrict__ d1, u16* __restrict__ d2, u16* __restrict__ d3,
  u16* __restrict__ d4, u16* __restrict__ d5, u16* __restrict__ d6)
{
  int bx = blockIdx.x, tid = threadIdx.x;
  if (bx < 35200){                     // inputs [25600 x 1400] -> bf16 padded 1408
    long long i4 = (long long)bx*256 + tid;      // < 9011200 exactly
    long long o = i4*4;
    int r = (int)(o / 1408);
    int c = (int)(o % 1408);
    us4 d;
    if (c + 4 <= 1400){
      f32x4 v = *(const f32x4*)&in0[(long long)r*1400 + c];
      d[0]=f2b(v[0]); d[1]=f2b(v[1]); d[2]=f2b(v[2]); d[3]=f2b(v[3]);
    } else {
      for (int k=0;k<4;k++){ int cc=c+k; d[k] = (cc<1400)? f2b(in0[(long long)r*1400+cc]) : (u16)0; }
    }
    *(us4*)&A0[(long long)r*1408 + c] = d;
  } else if (bx < 36608){              // emb [1400x256] -> embT [256x1408] bf16
    int idx = (bx-35200)*256 + tid;    // < 360448 exactly
    int n = idx / 1408, k = idx % 1408;
    embT[idx] = (k < 1400) ? f2b(emb[(long long)k*256 + n]) : (u16)0;
  } else {                             // 7 weight arrays fp32 -> bf16
    long long q = (long long)(bx-36608)*256 + tid;   // < 311296 exactly
    const float* src; u16* dst; long long rel;
    if      (q < 65536)  { src=s0; dst=d0; rel=q; }
    else if (q < 131072) { src=s1; dst=d1; rel=q-65536; }
    else if (q < 196608) { src=s2; dst=d2; rel=q-131072; }
    else if (q < 262144) { src=s3; dst=d3; rel=q-196608; }
    else if (q < 278528) { src=s4; dst=d4; rel=q-262144; }
    else if (q < 294912) { src=s5; dst=d5; rel=q-278528; }
    else                 { src=s6; dst=d6; rel=q-294912; }
    long long o = rel*4;
    f32x4 v = *(const f32x4*)&src[o];
    us4 d; d[0]=f2b(v[0]); d[1]=f2b(v[1]); d[2]=f2b(v[2]); d[3]=f2b(v[3]);
    *(us4*)&dst[o] = d;
  }
}

// ---------------- init: zero E + ctx + counters ----------------
__global__ __launch_bounds__(256) void k_init(float* __restrict__ E, float* __restrict__ ctx,
                                              int* __restrict__ cnts){
  int i = blockIdx.x*256 + threadIdx.x;
  if (i < 32768) E[i] = 0.f;
  else if (i < 65536) ctx[i-32768] = 0.f;
  else if (i < 65568) cnts[i-65536] = 0;
}

// ---------------- bf16 MFMA GEMM: C[M,N] = A[M,K] * Bt[N,K]^T -------------
// EPI 1: write fp32 + bf16 copies
// EPI 6: dual bf16 ux output, +bias pair (blockIdx.y>=8 -> second set)
// EPI 5: ctx[b,col] += emb[row,col]*tanh(acc)*alpha[row]  (LDS + global atomics)
template<int EPI>
__global__ __launch_bounds__(256) void k_gemm(const u16* __restrict__ A, const u16* __restrict__ Bt,
    int N, int K,
    float* __restrict__ Cf, u16* __restrict__ Cb,
    const float* __restrict__ bias1, const float* __restrict__ bias2,
    const u16* __restrict__ Bt2, u16* __restrict__ Cb2,
    const float* __restrict__ bias3, const float* __restrict__ bias4,
    const float* __restrict__ emb, const float* __restrict__ alpha)
{
  __shared__ __align__(16) u16 As[128*64];
  __shared__ __align__(16) u16 Bs[128*64];
  __shared__ float red[2][128];
  const int tid = threadIdx.x;
  const int l = tid & 63, w = tid >> 6;
  const int quad = l >> 4, lb = l & 15;
  const int wr = w >> 1, wc = w & 1;
  const long long m0 = (long long)blockIdx.x * 128;
  int n0 = blockIdx.y * 128;
  if (EPI==6 && blockIdx.y >= 8){
    Bt = Bt2; Cb = Cb2; bias1 = bias3; bias2 = bias4; n0 = (blockIdx.y-8)*128;
  }

  f32x4 acc[4][4];
  #pragma unroll
  for (int i=0;i<4;i++)
    #pragma unroll
    for (int j=0;j<4;j++) acc[i][j] = (f32x4){0.f,0.f,0.f,0.f};

  for (int kk = 0; kk < K; kk += 64){
    #pragma unroll
    for (int it=0; it<4; ++it){      // 128x64 bf16 tile, XOR-swizzled 16B slots
      int slot = it*256 + tid;
      int m = slot >> 3;
      int q = (slot & 7) ^ (m & 7);
      gl16(A + (m0+m)*K + kk + q*8, &As[slot*8]);
    }
    #pragma unroll
    for (int it=0; it<4; ++it){
      int slot = it*256 + tid;
      int m = slot >> 3;
      int q = (slot & 7) ^ (m & 7);
      gl16(Bt + (long long)(n0+m)*K + kk + q*8, &Bs[slot*8]);
    }
    __syncthreads();
    #pragma unroll
    for (int ks=0; ks<2; ++ks){
      int kq = quad + ks*4;
      bf16x8 af[4], bfr[4];
      #pragma unroll
      for (int i=0;i<4;i++){ int m = wr*64 + i*16 + lb; af[i]  = *(const bf16x8*)&As[m*64 + ((kq ^ (m&7))*8)]; }
      #pragma unroll
      for (int j=0;j<4;j++){ int n = wc*64 + j*16 + lb; bfr[j] = *(const bf16x8*)&Bs[n*64 + ((kq ^ (n&7))*8)]; }
      #pragma unroll
      for (int i=0;i<4;i++)
        #pragma unroll
        for (int j=0;j<4;j++)
          acc[i][j] = MFMA(af[i], bfr[j], acc[i][j]);
    }
    __syncthreads();
  }

  if (EPI==5){
    const int b0 = (int)(m0 / 200);
    red[tid>>7][tid&127] = 0.f;
    __syncthreads();
    #pragma unroll
    for (int i=0;i<4;i++){
      #pragma unroll
      for (int j=0;j<4;j++){
        int col = wc*64 + j*16 + lb;          // 0..127 within n0 tile
        #pragma unroll
        for (int r=0;r<4;r++){
          long long row = m0 + wr*64 + i*16 + quad*4 + r;
          long long o = row*N + n0 + col;
          float v = emb[o] * tanhx(acc[i][j][r]) * alpha[row];
          atomicAdd(&red[(int)(row/200) - b0][col], v);
        }
      }
    }
    __syncthreads();
    int bl = tid >> 7, col = tid & 127;       // 256 threads cover [2][128]
    int bb = b0 + bl;
    if (bb < 128) atomicAdd(&Cf[bb*256 + n0 + col], red[bl][col]);
    return;
  }

  #pragma unroll
  for (int i=0;i<4;i++){
    #pragma unroll
    for (int j=0;j<4;j++){
      int col = n0 + wc*64 + j*16 + lb;
      #pragma unroll
      for (int r=0;r<4;r++){
        long long row = m0 + wr*64 + i*16 + quad*4 + r;
        long long o = row*N + col;
        float v = acc[i][j][r];
        if (EPI==1){ Cf[o]=v; Cb[o]=f2b(v); }
        else if (EPI==6){ Cb[o] = f2b(v + bias1[col] + bias2[col]); }
      }
    }
  }
}

// ---------------- persistent TimeLSTM scan ----------------
// 64 WGs. Groups of 4 (same lstm, 4 j-chunks of 64) exchange h,c per step.
// Groups are formed dynamically by actual XCD (HW_REG_XCC_ID + one-time MALL
// registration/rendezvous): same-XCD groups exchange at the shared per-XCD L2
// (workgroup-scope stores, L2-point RMW flag polls, sc0 atomic-add(0) data
// loads -- atomics are never L1-served). Writers ALWAYS dual-publish a MALL
// mirror; readers sticky-fall-back to it after a bounded poll, so correctness
// never depends on WG->XCD placement.
__global__ __launch_bounds__(256,1) void k_scan(
  const u16* __restrict__ Wall1, const u16* __restrict__ Wd1, const float* __restrict__ Wd1b,
  const u16* __restrict__ ux1, const float* __restrict__ h01, const float* __restrict__ c01,
  const u16* __restrict__ Wall2, const u16* __restrict__ Wd2, const float* __restrict__ Wd2b,
  const u16* __restrict__ ux2, const float* __restrict__ h02, const float* __restrict__ c02,
  const float* __restrict__ ts, const float* __restrict__ wa,
  float* __restrict__ E, u16* __restrict__ out2,
  u64* __restrict__ pay, unsigned* __restrict__ flg,
  u64* __restrict__ mpay, unsigned* __restrict__ mflg,
  int* __restrict__ cntp, int* __restrict__ totalp, int* __restrict__ fbp)
{
  __shared__ __align__(16) u16 hb[16][264];
  __shared__ __align__(16) u16 cb[16][264];
  __shared__ int bcast[3];
  __shared__ int lok;                  // sticky: local (L2) path usable

  const int bi = blockIdx.x;
  const int lstm = bi >> 5;
  const int tid = threadIdx.x;

  // ---- one-time group formation by actual XCD ----
  if (tid == 0){
    int xcd;
    asm volatile("s_getreg_b32 %0, hwreg(HW_REG_XCC_ID)" : "=s"(xcd));
    xcd &= 7;
    int slot = __hip_atomic_fetch_add(&cntp[lstm*8+xcd], 1, __ATOMIC_RELAXED, __HIP_MEMORY_SCOPE_AGENT);
    __hip_atomic_fetch_add(totalp, 1, __ATOMIC_RELAXED, __HIP_MEMORY_SCOPE_AGENT);
    while (__hip_atomic_load(totalp, __ATOMIC_RELAXED, __HIP_MEMORY_SCOPE_AGENT) < 64)
      __builtin_amdgcn_s_sleep(8);
    int c[8];
    #pragma unroll
    for (int x=0;x<8;x++)
      c[x] = __hip_atomic_load(&cntp[lstm*8+x], __ATOMIC_RELAXED, __HIP_MEMORY_SCOPE_AGENT);
    int myq = slot>>2, bc, jw, lg;
    if (myq < (c[xcd]>>2)){            // complete same-XCD quad
      int base=0;
      for (int x=0;x<xcd;x++) base += c[x]>>2;
      bc = base + myq; jw = slot&3; lg = 1;
    } else {                           // leftover -> fallback (MALL) group
      int C=0;
      for (int x=0;x<8;x++) C += c[x]>>2;
      int fb = __hip_atomic_fetch_add(&fbp[lstm], 1, __ATOMIC_RELAXED, __HIP_MEMORY_SCOPE_AGENT);
      bc = C + (fb>>2); jw = fb&3; lg = 0;
    }
    bcast[0]=bc; bcast[1]=jw; bcast[2]=lg; lok = lg;
  }
  __syncthreads();
  const int bc = bcast[0];
  const int jw = bcast[1];
  const int grp = lstm*8 + bc;         // 0..15 exchange namespace

  const u16* Wall  = lstm ? Wall2 : Wall1;
  const u16* Wd    = lstm ? Wd2   : Wd1;
  const float* Wdb = lstm ? Wd2b  : Wd1b;
  const u16* ux    = lstm ? ux2   : ux1;
  const float* h0  = lstm ? h02   : h01;
  const float* c0  = lstm ? c02   : c01;

  const int l = tid & 63, w = tid >> 6;
  const int quad = l >> 4, lb = l & 15;
  const int bg = bc*16 + lb;            // lane's global batch
  const int jwave = jw*64 + w*16;       // wave's 16 output rows (per gate)
  const int jlane = jwave + quad*4;     // lane's 4 j rows (C-layout)
  const int bb = tid >> 4, jj = tid & 15, j0 = jj*16;   // refill role
  const int wjw = jj >> 2;              // writer WG of my refill block

  // ---- one-time: weight fragments into registers (A-frag: m=lb, k=quad*8+i)
  bf16x8 wfA[4][8], wdA[8];
  #pragma unroll
  for (int g=0; g<4; ++g)
    #pragma unroll
    for (int kk=0; kk<8; ++kk){
      wfA[g][kk] = *(const bf16x8*)&Wall[(long long)(g*256 + jwave + lb)*256 + kk*32 + quad*8];
      KEEP(wfA[g][kk]);
    }
  #pragma unroll
  for (int kk=0; kk<8; ++kk){
    wdA[kk] = *(const bf16x8*)&Wd[(long long)(jwave + lb)*256 + kk*32 + quad*8];
    KEEP(wdA[kk]);
  }

  f32x4 bcs  = *(const f32x4*)&Wdb[jlane];
  f32x4 wav  = *(const f32x4*)&wa[jlane];
  f32x4 creg = *(const f32x4*)&c0[(long long)bg*256 + jlane];

  // ---- init LDS h/c (full 256 j for our 16 batches), bf16
  #pragma unroll
  for (int kq=0; kq<4; ++kq){
    f32x4 hv = *(const f32x4*)&h0[(long long)(bc*16+bb)*256 + j0 + kq*4];
    f32x4 cv = *(const f32x4*)&c0[(long long)(bc*16+bb)*256 + j0 + kq*4];
    us4 hp0, cp0;
    #pragma unroll
    for (int r=0;r<4;++r){ hp0[r]=f2b(hv[r]); cp0[r]=f2b(cv[r]); }
    *(us4*)&hb[bb][j0+kq*4] = hp0;
    *(us4*)&cb[bb][j0+kq*4] = cp0;
  }
  __syncthreads();

  us4 uxr[4];
  #pragma unroll
  for (int g=0; g<4; ++g)
    uxr[g] = *(const us4*)&ux[(long long)bg*200*1024 + g*256 + jlane];
  float tcur = ts[(long long)bg*200];

  for (int s=0; s<200; ++s){
    const int lk = lok;                 // stable since last B2
    // consume ux(s) into fp32 accumulators, then immediately prefetch ux(s+1)
    f32x4 ag[4];
    #pragma unroll
    for (int g=0; g<4; ++g)
      #pragma unroll
      for (int r=0; r<4; ++r) ag[g][r] = b2f(uxr[g][r]);
    float tnx = 0.f;
    if (s < 199){
      #pragma unroll
      for (int g=0; g<4; ++g)
        uxr[g] = *(const us4*)&ux[((long long)bg*200 + s+1)*1024 + g*256 + jlane];
      tnx = ts[(long long)bg*200 + s+1];
    }
    // c_s1 pre-act: Wd GEMV over cb
    f32x4 ad = bcs;
    #pragma unroll
    for (int kk=0;kk<8;++kk){
      bf16x8 cf = *(const bf16x8*)&cb[lb][kk*32 + quad*8];
      ad = MFMA(wdA[kk], cf, ad);
    }
    // gates: ux + Wall GEMV over hb
    #pragma unroll
    for (int kk=0;kk<8;++kk){
      bf16x8 hf = *(const bf16x8*)&hb[lb][kk*32 + quad*8];
      #pragma unroll
      for (int g=0; g<4; ++g) ag[g] = MFMA(wfA[g][kk], hf, ag[g]);
    }
    // elementwise update (fp32 c carried in regs)
    f32x4 hn; us4 hp, cp;
    #pragma unroll
    for (int r=0;r<4;++r){
      float cs1 = tanhx(ad[r]);
      float cadj = creg[r] + cs1*(tcur - 1.0f);
      float fg = sigm(ag[0][r]);
      float ig = sigm(ag[1][r]);
      float og = sigm(ag[2][r]);
      float cg = sigm(ag[3][r]);
      float cn = fg*cadj + ig*cg;
      float hv = og*tanhx(cn);
      creg[r]=cn; hn[r]=hv;
      hp[r]=f2b(hv); cp[r]=f2b(cn);
    }
    // outputs: lstm0 -> E partial (folded attention dot), lstm1 -> out2
    if (lstm==0){
      float e = hn[0]*wav[0] + hn[1]*wav[1] + hn[2]*wav[2] + hn[3]*wav[3];
      e += __shfl_xor(e, 16, 64);
      e += __shfl_xor(e, 32, 64);
      if (l < 16)
        __hip_atomic_fetch_add(&E[(long long)bg*256 + s], e, __ATOMIC_RELAXED, __HIP_MEMORY_SCOPE_AGENT);
    } else {
      *(us4*)&out2[((long long)bg*200 + s)*256 + jlane] = hp;
    }
    // ---- exchange h,c with the 3 sibling j-WGs ----
    if (s < 199){
      const int slot = (s+1)&1;
      const int fbase = (slot*16+grp)*16;
      u64 h64, c64;
      __builtin_memcpy(&h64,&hp,8); __builtin_memcpy(&c64,&cp,8);
      long long W = ((long long)(slot*16+grp)*16 + lb)*128 + ((jlane>>2)<<1);
      if (lk){
        __hip_atomic_store(&pay[W],   h64, __ATOMIC_RELAXED, __HIP_MEMORY_SCOPE_WORKGROUP);
        __hip_atomic_store(&pay[W+1], c64, __ATOMIC_RELAXED, __HIP_MEMORY_SCOPE_WORKGROUP);
      }
      __hip_atomic_store(&mpay[W],   h64, __ATOMIC_RELAXED, __HIP_MEMORY_SCOPE_AGENT);
      __hip_atomic_store(&mpay[W+1], c64, __ATOMIC_RELAXED, __HIP_MEMORY_SCOPE_AGENT);
      __syncthreads();                  // B1: stores acked (L2 + MALL mirror); LDS reads done
      if (tid == 0){
        if (lk) __hip_atomic_store(&flg[fbase+jw], (unsigned)(s+1), __ATOMIC_RELAXED, __HIP_MEMORY_SCOPE_WORKGROUP);
        __hip_atomic_store(&mflg[fbase+jw], (unsigned)(s+1), __ATOMIC_RELAXED, __HIP_MEMORY_SCOPE_AGENT);
      }
      // own chunk: registers -> LDS
      *(us4*)&hb[lb][jlane] = hp;
      *(us4*)&cb[lb][jlane] = cp;
      // pollers: one thread per sibling flag
      if (tid < 4 && tid != jw){
        const unsigned tgt = (unsigned)(s+1);
        bool ok = false;
        if (lk){
          for (int it=0; it<3000; ++it){
            unsigned v = __hip_atomic_fetch_add(&flg[fbase+tid], 65536u, __ATOMIC_RELAXED, __HIP_MEMORY_SCOPE_WORKGROUP);
            if ((v & 0xFFFFu) == tgt){ ok = true; break; }
            __builtin_amdgcn_s_sleep(2);
          }
          if (!ok) lok = 0;             // sticky degrade to MALL mirror
        }
        if (!ok){
          while (__hip_atomic_load(&mflg[fbase+tid], __ATOMIC_RELAXED, __HIP_MEMORY_SCOPE_AGENT) != tgt)
            __builtin_amdgcn_s_sleep(2);
        }
      }
      __syncthreads();                  // B_poll: all sibling flags observed
      if (wjw != jw){
        const int lk2 = lok;
        long long R = ((long long)(slot*16+grp)*16 + bb)*128 + jj*8;
        u64 h0v,c0v,h1v,c1v,h2v,c2v,h3v,c3v;
        if (lk2){
          u64 a = (u64)(unsigned long long)(uintptr_t)&pay[R];
          u64 z = 0;
          asm volatile(
            "global_atomic_add_x2 %[o0], %[a], %[z], off sc0\n\t"
            "global_atomic_add_x2 %[o1], %[a], %[z], off offset:8 sc0\n\t"
            "global_atomic_add_x2 %[o2], %[a], %[z], off offset:16 sc0\n\t"
            "global_atomic_add_x2 %[o3], %[a], %[z], off offset:24 sc0\n\t"
            "global_atomic_add_x2 %[o4], %[a], %[z], off offset:32 sc0\n\t"
            "global_atomic_add_x2 %[o5], %[a], %[z], off offset:40 sc0\n\t"
            "global_atomic_add_x2 %[o6], %[a], %[z], off offset:48 sc0\n\t"
            "global_atomic_add_x2 %[o7], %[a], %[z], off offset:56 sc0\n\t"
            "s_waitcnt vmcnt(0)"
            : [o0]"=v"(h0v), [o1]"=v"(c0v), [o2]"=v"(h1v), [o3]"=v"(c1v),
              [o4]"=v"(h2v), [o5]"=v"(c2v), [o6]"=v"(h3v), [o7]"=v"(c3v)
            : [a]"v"(a), [z]"v"(z)
            : "memory");
        } else {
          h0v = __hip_atomic_load(&mpay[R+0], __ATOMIC_RELAXED, __HIP_MEMORY_SCOPE_AGENT);
          c0v = __hip_atomic_load(&mpay[R+1], __ATOMIC_RELAXED, __HIP_MEMORY_SCOPE_AGENT);
          h1v = __hip_atomic_load(&mpay[R+2], __ATOMIC_RELAXED, __HIP_MEMORY_SCOPE_AGENT);
          c1v = __hip_atomic_load(&mpay[R+3], __ATOMIC_RELAXED, __HIP_MEMORY_SCOPE_AGENT);
          h2v = __hip_atomic_load(&mpay[R+4], __ATOMIC_RELAXED, __HIP_MEMORY_SCOPE_AGENT);
          c2v = __hip_atomic_load(&mpay[R+5], __ATOMIC_RELAXED, __HIP_MEMORY_SCOPE_AGENT);
          h3v = __hip_atomic_load(&mpay[R+6], __ATOMIC_RELAXED, __HIP_MEMORY_SCOPE_AGENT);
          c3v = __hip_atomic_load(&mpay[R+7], __ATOMIC_RELAXED, __HIP_MEMORY_SCOPE_AGENT);
        }
        *(u64*)&hb[bb][j0+ 0] = h0v;  *(u64*)&cb[bb][j0+ 0] = c0v;
        *(u64*)&hb[bb][j0+ 4] = h1v;  *(u64*)&cb[bb][j0+ 4] = c1v;
        *(u64*)&hb[bb][j0+ 8] = h2v;  *(u64*)&cb[bb][j0+ 8] = c2v;
        *(u64*)&hb[bb][j0+12] = h3v;  *(u64*)&cb[bb][j0+12] = c3v;
      }
      tcur = tnx;
      __syncthreads();                  // B2: LDS h/c(s+1) complete
    }
  }
}

// ---------------- softmax over precomputed E -> alpha ----------------
__global__ __launch_bounds__(256) void k_attn(const float* __restrict__ E, float* __restrict__ alpha){
  __shared__ float buf[256];
  int b = blockIdx.x, tid = threadIdx.x;
  float Ev = (tid < 200) ? E[(long long)b*256 + tid] : -1e30f;
  buf[tid]=Ev; __syncthreads();
  for (int st=128; st>0; st>>=1){ if (tid<st) buf[tid]=fmaxf(buf[tid],buf[tid+st]); __syncthreads(); }
  float mx = buf[0]; __syncthreads();
  float e = (tid<200)? __expf(Ev-mx) : 0.f;
  buf[tid]=e; __syncthreads();
  for (int st=128; st>0; st>>=1){ if (tid<st) buf[tid]+=buf[tid+st]; __syncthreads(); }
  float sm = buf[0];
  if (tid<200) alpha[(long long)b*200+tid] = e/sm;
}

// ---------------- out = ctx @ Wout^T ----------------
__global__ __launch_bounds__(128) void k_out(const float* __restrict__ ctx, const float* __restrict__ Wout,
                                             float* __restrict__ out){
  __shared__ float cs[256];
  int b = blockIdx.x, t = threadIdx.x;
  cs[t] = ctx[b*256+t]; cs[t+128] = ctx[b*256+t+128];
  __syncthreads();
  const float* wr = Wout + (long long)t*256;
  float a0=0,a1=0,a2=0,a3=0;
  for (int j=0;j<256;j+=4){
    f32x4 v = *(const f32x4*)&wr[j];
    a0+=v[0]*cs[j]; a1+=v[1]*cs[j+1]; a2+=v[2]*cs[j+2]; a3+=v[3]*cs[j+3];
  }
  out[(long long)b*128 + t] = (a0+a1)+(a2+a3);
}

extern "C" void kernel_launch(void* const* d_in, const int* in_sizes, int n_in,
                              void* d_out, int out_size, void* d_ws, size_t ws_size,
                              hipStream_t stream)
{
  (void)in_sizes; (void)n_in; (void)out_size; (void)ws_size;
  const float* inputs = (const float*)d_in[0];
  const float* tstamp = (const float*)d_in[1];
  const float* emb    = (const float*)d_in[2];
  const float* Wall1w = (const float*)d_in[3];
  const float* Wall1b = (const float*)d_in[4];
  const float* Uall1w = (const float*)d_in[5];
  const float* Uall1b = (const float*)d_in[6];
  const float* Wd1w   = (const float*)d_in[7];
  const float* Wd1b   = (const float*)d_in[8];
  const float* Wall2w = (const float*)d_in[9];
  const float* Wall2b = (const float*)d_in[10];
  const float* Uall2w = (const float*)d_in[11];
  const float* Uall2b = (const float*)d_in[12];
  const float* Wd2w   = (const float*)d_in[13];
  const float* Wd2b   = (const float*)d_in[14];
  const float* wa     = (const float*)d_in[15];
  const float* Wbw    = (const float*)d_in[16];
  const float* Woutw  = (const float*)d_in[17];
  const float* h01    = (const float*)d_in[18];
  const float* c01    = (const float*)d_in[19];
  const float* h02    = (const float*)d_in[20];
  const float* c02    = (const float*)d_in[21];

  char* ws = (char*)d_ws;
  u16*   ux1   = (u16*)  (ws + 0);              // 25600*1024*2 = 52428800
  u16*   ux2   = (u16*)  (ws + 52428800LL);
  float* embF  = (float*)(ws + 104857600LL);    // 26214400
  u16*   embB  = (u16*)  (ws + 131072000LL);    // 13107200
  char*  scr   =          ws + 144179200LL;     // 72089600 region (A0 overlay)
  u16*   A0    = (u16*)scr;                     // 72089600 (dead after embed GEMM)
  u16*   out2  = (u16*)  (scr + 0);             // 13107200
  float* E     = (float*)(scr + 13107200LL);    // 131072 (stride-256 padded)
  float* ctx   = (float*)(scr + 13238272LL);    // 131072
  float* alpha = (float*)(scr + 13369344LL);    // 102400
  u64*   pay   = (u64*)  (scr + 13471744LL);    // 524288 (1KB-aligned groups)
  unsigned* flg= (unsigned*)(scr + 13996032LL); // 2048 (64B per group)
  u64*   mpay  = (u64*)  (scr + 13998080LL);    // 524288
  unsigned* mflg=(unsigned*)(scr + 14522368LL); // 2048
  int*   cnts  = (int*)  (scr + 14524416LL);    // 128: cnt[16], total, fbcnt[2]
  u16* embT    = (u16*)(ws + 216268800LL);      // 720896
  u16* Wall1B  = (u16*)(ws + 216989696LL);      // 524288
  u16* Wall2B  = (u16*)(ws + 217513984LL);
  u16* Uall1B  = (u16*)(ws + 218038272LL);
  u16* Uall2B  = (u16*)(ws + 218562560LL);
  u16* Wd1B    = (u16*)(ws + 219086848LL);      // 131072
  u16* Wd2B    = (u16*)(ws + 219217920LL);
  u16* WbB     = (u16*)(ws + 219348992LL);
  // total ws: ~219.5 MB (was ~324 MB)

  int* cntp   = cnts;        // 16
  int* totalp = cnts + 16;   // 1
  int* fbp    = cnts + 17;   // 2

  // 1) all conversions (inputs, emb^T, 7 weights) in one launch
  k_prep<<<37824, 256, 0, stream>>>(inputs, A0, emb, embT,
                                    Wall1w, Wall2w, Uall1w, Uall2w, Wd1w, Wd2w, Wbw,
                                    Wall1B, Wall2B, Uall1B, Uall2B, Wd1B, Wd2B, WbB);
  // 2) embedded = inputs @ emb  (fp32 + bf16 copies)
  k_gemm<1><<<dim3(200,2), 256, 0, stream>>>(A0, embT, 256, 1408, embF, embB,
                                             nullptr, nullptr, nullptr, nullptr,
                                             nullptr, nullptr, nullptr, nullptr);
  // 3) ux1,ux2 = bf16( embedded @ Uall{1,2}^T + (Uall_b + Wall_b) ), one launch
  k_gemm<6><<<dim3(200,16), 256, 0, stream>>>(embB, Uall1B, 1024, 256, nullptr, ux1,
                                              Uall1b, Wall1b,
                                              Uall2B, ux2, Uall2b, Wall2b,
                                              nullptr, nullptr);
  // 4) zero E + ctx + formation counters (after A0 is dead)
  k_init<<<257, 256, 0, stream>>>(E, ctx, cnts);
  // 5) both TimeLSTM scans (64 persistent WGs, XCD-local L2 exchange)
  k_scan<<<64, 256, 0, stream>>>(Wall1B, Wd1B, Wd1b, ux1, h01, c01,
                                 Wall2B, Wd2B, Wd2b, ux2, h02, c02,
                                 tstamp, wa, E, out2,
                                 pay, flg, mpay, mflg, cntp, totalp, fbp);
  // 6) alpha = softmax(E)
  k_attn<<<128, 256, 0, stream>>>(E, alpha);
  // 7) ctx += sum_s emb * tanh(out2 @ Wb^T) * alpha  (fused, no P buffer)
  k_gemm<5><<<dim3(200,2), 256, 0, stream>>>(out2, WbB, 256, 256, ctx, nullptr,
                                             nullptr, nullptr, nullptr, nullptr,
                                             nullptr, nullptr, embF, alpha);
  // 8) out = ctx @ Wout^T
  k_out<<<128, 128, 0, stream>>>(ctx, Woutw, (float*)d_out);
}

// Round 6
// 1623.627 us; speedup vs baseline: 1.1249x; 1.1249x over previous
//
#include <hip/hip_runtime.h>

typedef unsigned short u16;
typedef unsigned long long u64;
typedef __attribute__((ext_vector_type(8))) short bf16x8;
typedef __attribute__((ext_vector_type(4))) float f32x4;
typedef __attribute__((ext_vector_type(4))) unsigned short us4;

#define MFMA(a,b,c) __builtin_amdgcn_mfma_f32_16x16x32_bf16((a),(b),(c),0,0,0)
#define KEEP(x) asm volatile("" : "+v"(x))

// B=128, SEQ=200, VOCAB=1400 (pad 1408), D=H=256, 4H=1024, NCLS=128, M=B*SEQ=25600

static __device__ __forceinline__ u16 f2b(float f){
  unsigned u = __float_as_uint(f);
  u += 0x7fffu + ((u >> 16) & 1u);          // RNE fp32 -> bf16
  return (u16)(u >> 16);
}
static __device__ __forceinline__ float b2f(u16 v){
  return __uint_as_float(((unsigned)v) << 16);
}
static __device__ __forceinline__ float sigm(float x){ return 1.0f/(1.0f+__expf(-x)); }
static __device__ __forceinline__ float tanhx(float x){
  x = fminf(fmaxf(x, -15.f), 15.f);
  float e = __expf(-2.f*x);
  return (1.f - e)/(1.f + e);
}
static __device__ __forceinline__ void gl16(const void* g, void* l){
  __builtin_amdgcn_global_load_lds((const __attribute__((address_space(1))) void*)g,
                                   (__attribute__((address_space(3))) void*)l, 16, 0, 0);
}

// ---------------- fused prep: inputs cvt + emb transpose-cvt + weights ----
__global__ __launch_bounds__(256) void k_prep(
  const float* __restrict__ in0, u16* __restrict__ A0,
  const float* __restrict__ emb, u16* __restrict__ embT,
  const float* __restrict__ s0, const float* __restrict__ s1, const float* __restrict__ s2,
  const float* __restrict__ s3, const float* __restrict__ s4, const float* __restrict__ s5,
  const float* __restrict__ s6,
  u16* __restrict__ d0, u16* __restrict__ d1, u16* __restrict__ d2, u16* __restrict__ d3,
  u16* __restrict__ d4, u16* __restrict__ d5, u16* __restrict__ d6)
{
  int bx = blockIdx.x, tid = threadIdx.x;
  if (bx < 35200){                     // inputs [25600 x 1400] -> bf16 padded 1408
    long long i4 = (long long)bx*256 + tid;      // < 9011200 exactly
    long long o = i4*4;
    int r = (int)(o / 1408);
    int c = (int)(o % 1408);
    us4 d;
    if (c + 4 <= 1400){
      f32x4 v = *(const f32x4*)&in0[(long long)r*1400 + c];
      d[0]=f2b(v[0]); d[1]=f2b(v[1]); d[2]=f2b(v[2]); d[3]=f2b(v[3]);
    } else {
      for (int k=0;k<4;k++){ int cc=c+k; d[k] = (cc<1400)? f2b(in0[(long long)r*1400+cc]) : (u16)0; }
    }
    *(us4*)&A0[(long long)r*1408 + c] = d;
  } else if (bx < 36608){              // emb [1400x256] -> embT [256x1408] bf16
    int idx = (bx-35200)*256 + tid;    // < 360448 exactly
    int n = idx / 1408, k = idx % 1408;
    embT[idx] = (k < 1400) ? f2b(emb[(long long)k*256 + n]) : (u16)0;
  } else {                             // 7 weight arrays fp32 -> bf16
    long long q = (long long)(bx-36608)*256 + tid;   // < 311296 exactly
    const float* src; u16* dst; long long rel;
    if      (q < 65536)  { src=s0; dst=d0; rel=q; }
    else if (q < 131072) { src=s1; dst=d1; rel=q-65536; }
    else if (q < 196608) { src=s2; dst=d2; rel=q-131072; }
    else if (q < 262144) { src=s3; dst=d3; rel=q-196608; }
    else if (q < 278528) { src=s4; dst=d4; rel=q-262144; }
    else if (q < 294912) { src=s5; dst=d5; rel=q-278528; }
    else                 { src=s6; dst=d6; rel=q-294912; }
    long long o = rel*4;
    f32x4 v = *(const f32x4*)&src[o];
    us4 d; d[0]=f2b(v[0]); d[1]=f2b(v[1]); d[2]=f2b(v[2]); d[3]=f2b(v[3]);
    *(us4*)&dst[o] = d;
  }
}

// ---------------- init: zero E + ctx ----------------
__global__ __launch_bounds__(256) void k_init(float* __restrict__ E, float* __restrict__ ctx){
  int i = blockIdx.x*256 + threadIdx.x;     // 256*256 = 65536 exactly
  if (i < 32768) E[i] = 0.f;
  else ctx[i-32768] = 0.f;
}

// ---------------- bf16 MFMA GEMM: C[M,N] = A[M,K] * Bt[N,K]^T -------------
// EPI 1: write fp32 + bf16 copies
// EPI 6: dual bf16 ux output, +bias pair (blockIdx.y>=8 -> second set)
// EPI 5: ctx[b,col] += emb[row,col]*tanh(acc)*alpha[row]  (LDS + global atomics)
template<int EPI>
__global__ __launch_bounds__(256) void k_gemm(const u16* __restrict__ A, const u16* __restrict__ Bt,
    int N, int K,
    float* __restrict__ Cf, u16* __restrict__ Cb,
    const float* __restrict__ bias1, const float* __restrict__ bias2,
    const u16* __restrict__ Bt2, u16* __restrict__ Cb2,
    const float* __restrict__ bias3, const float* __restrict__ bias4,
    const float* __restrict__ emb, const float* __restrict__ alpha)
{
  __shared__ __align__(16) u16 As[128*64];
  __shared__ __align__(16) u16 Bs[128*64];
  __shared__ float red[2][128];
  const int tid = threadIdx.x;
  const int l = tid & 63, w = tid >> 6;
  const int quad = l >> 4, lb = l & 15;
  const int wr = w >> 1, wc = w & 1;
  const long long m0 = (long long)blockIdx.x * 128;
  int n0 = blockIdx.y * 128;
  if (EPI==6 && blockIdx.y >= 8){
    Bt = Bt2; Cb = Cb2; bias1 = bias3; bias2 = bias4; n0 = (blockIdx.y-8)*128;
  }

  f32x4 acc[4][4];
  #pragma unroll
  for (int i=0;i<4;i++)
    #pragma unroll
    for (int j=0;j<4;j++) acc[i][j] = (f32x4){0.f,0.f,0.f,0.f};

  for (int kk = 0; kk < K; kk += 64){
    #pragma unroll
    for (int it=0; it<4; ++it){      // 128x64 bf16 tile, XOR-swizzled 16B slots
      int slot = it*256 + tid;
      int m = slot >> 3;
      int q = (slot & 7) ^ (m & 7);
      gl16(A + (m0+m)*K + kk + q*8, &As[slot*8]);
    }
    #pragma unroll
    for (int it=0; it<4; ++it){
      int slot = it*256 + tid;
      int m = slot >> 3;
      int q = (slot & 7) ^ (m & 7);
      gl16(Bt + (long long)(n0+m)*K + kk + q*8, &Bs[slot*8]);
    }
    __syncthreads();
    #pragma unroll
    for (int ks=0; ks<2; ++ks){
      int kq = quad + ks*4;
      bf16x8 af[4], bfr[4];
      #pragma unroll
      for (int i=0;i<4;i++){ int m = wr*64 + i*16 + lb; af[i]  = *(const bf16x8*)&As[m*64 + ((kq ^ (m&7))*8)]; }
      #pragma unroll
      for (int j=0;j<4;j++){ int n = wc*64 + j*16 + lb; bfr[j] = *(const bf16x8*)&Bs[n*64 + ((kq ^ (n&7))*8)]; }
      #pragma unroll
      for (int i=0;i<4;i++)
        #pragma unroll
        for (int j=0;j<4;j++)
          acc[i][j] = MFMA(af[i], bfr[j], acc[i][j]);
    }
    __syncthreads();
  }

  if (EPI==5){
    const int b0 = (int)(m0 / 200);
    red[tid>>7][tid&127] = 0.f;
    __syncthreads();
    #pragma unroll
    for (int i=0;i<4;i++){
      #pragma unroll
      for (int j=0;j<4;j++){
        int col = wc*64 + j*16 + lb;          // 0..127 within n0 tile
        #pragma unroll
        for (int r=0;r<4;r++){
          long long row = m0 + wr*64 + i*16 + quad*4 + r;
          long long o = row*N + n0 + col;
          float v = emb[o] * tanhx(acc[i][j][r]) * alpha[row];
          atomicAdd(&red[(int)(row/200) - b0][col], v);
        }
      }
    }
    __syncthreads();
    int bl = tid >> 7, col = tid & 127;       // 256 threads cover [2][128]
    int bb = b0 + bl;
    if (bb < 128) atomicAdd(&Cf[bb*256 + n0 + col], red[bl][col]);
    return;
  }

  #pragma unroll
  for (int i=0;i<4;i++){
    #pragma unroll
    for (int j=0;j<4;j++){
      int col = n0 + wc*64 + j*16 + lb;
      #pragma unroll
      for (int r=0;r<4;r++){
        long long row = m0 + wr*64 + i*16 + quad*4 + r;
        long long o = row*N + col;
        float v = acc[i][j][r];
        if (EPI==1){ Cf[o]=v; Cb[o]=f2b(v); }
        else if (EPI==6){ Cb[o] = f2b(v + bias1[col] + bias2[col]); }
      }
    }
  }
}

// ---------------- persistent TimeLSTM scan (R3 MALL protocol, no LDS) -----
// 64 WGs: bi>>5 = lstm, (bi>>2)&7 = batch chunk of 16, bi&3 = j-chunk of 64.
// h,c B-operand fragments live in REGISTERS. Exchange per step: relaxed
// agent-scope 8B stores of own chunk (layout = [batch][j], exactly MFMA
// B-fragment order) -> ONE barrier (vmcnt drain = MALL ack) -> tid0 publishes
// seq flag -> each wave autonomously polls the 3 sibling flags (lanes 0-2 +
// ballot) -> direct agent-scope loads refill the B-fragments. No LDS staging,
// no second barrier, no cache-maintenance ops.
__global__ __launch_bounds__(256,1) void k_scan(
  const u16* __restrict__ Wall1, const u16* __restrict__ Wd1, const float* __restrict__ Wd1b,
  const u16* __restrict__ ux1, const float* __restrict__ h01, const float* __restrict__ c01,
  const u16* __restrict__ Wall2, const u16* __restrict__ Wd2, const float* __restrict__ Wd2b,
  const u16* __restrict__ ux2, const float* __restrict__ h02, const float* __restrict__ c02,
  const float* __restrict__ ts, const float* __restrict__ wa,
  float* __restrict__ E, u16* __restrict__ out2,
  u16* __restrict__ mpay, unsigned* __restrict__ mflg)
{
  const int bi = blockIdx.x;
  const int lstm = bi >> 5;
  const int bc   = (bi >> 2) & 7;
  const int jw   = bi & 3;
  const int grp  = bi >> 2;            // 0..15, distinct per (lstm,bc)
  const u16* Wall  = lstm ? Wall2 : Wall1;
  const u16* Wd    = lstm ? Wd2   : Wd1;
  const float* Wdb = lstm ? Wd2b  : Wd1b;
  const u16* ux    = lstm ? ux2   : ux1;
  const float* h0  = lstm ? h02   : h01;
  const float* c0  = lstm ? c02   : c01;

  const int tid = threadIdx.x;
  const int l = tid & 63, w = tid >> 6;
  const int quad = l >> 4, lb = l & 15;
  const int bg = bc*16 + lb;            // lane's global batch
  const int jwave = jw*64 + w*16;       // wave's 16 output rows (per gate)
  const int jlane = jwave + quad*4;     // lane's 4 j rows (C-layout)
  const int sib = (l < 3) ? (l + (l >= jw ? 1 : 0)) : 0;   // poll targets

  // ---- one-time: weight fragments into registers (A-frag: m=lb, k=quad*8+i)
  bf16x8 wfA[4][8], wdA[8];
  #pragma unroll
  for (int g=0; g<4; ++g)
    #pragma unroll
    for (int kk=0; kk<8; ++kk){
      wfA[g][kk] = *(const bf16x8*)&Wall[(long long)(g*256 + jwave + lb)*256 + kk*32 + quad*8];
      KEEP(wfA[g][kk]);
    }
  #pragma unroll
  for (int kk=0; kk<8; ++kk){
    wdA[kk] = *(const bf16x8*)&Wd[(long long)(jwave + lb)*256 + kk*32 + quad*8];
    KEEP(wdA[kk]);
  }

  f32x4 bcs  = *(const f32x4*)&Wdb[jlane];
  f32x4 wav  = *(const f32x4*)&wa[jlane];
  f32x4 creg = *(const f32x4*)&c0[(long long)bg*256 + jlane];

  // ---- init h/c B-fragments from h0/c0 (fp32 -> bf16, B-layout: [b][k])
  bf16x8 hfr[8], cfr[8];
  #pragma unroll
  for (int kk=0; kk<8; ++kk){
    const float* hs = &h0[(long long)bg*256 + kk*32 + quad*8];
    const float* cs = &c0[(long long)bg*256 + kk*32 + quad*8];
    f32x4 ha = *(const f32x4*)hs, hb4 = *(const f32x4*)(hs+4);
    f32x4 ca = *(const f32x4*)cs, cb4 = *(const f32x4*)(cs+4);
    union { u16 u[8]; bf16x8 v; } th, tc;
    #pragma unroll
    for (int r=0;r<4;++r){
      th.u[r]=f2b(ha[r]); th.u[4+r]=f2b(hb4[r]);
      tc.u[r]=f2b(ca[r]); tc.u[4+r]=f2b(cb4[r]);
    }
    hfr[kk]=th.v; cfr[kk]=tc.v;
  }

  us4 uxr[4];
  #pragma unroll
  for (int g=0; g<4; ++g)
    uxr[g] = *(const us4*)&ux[(long long)bg*200*1024 + g*256 + jlane];
  float tcur = ts[(long long)bg*200];

  for (int s=0; s<200; ++s){
    // consume ux(s), then prefetch ux(s+1)/ts(s+1) early (hides HBM latency)
    f32x4 ag[4];
    #pragma unroll
    for (int g=0; g<4; ++g)
      #pragma unroll
      for (int r=0; r<4; ++r) ag[g][r] = b2f(uxr[g][r]);
    float tnx = 0.f;
    if (s < 199){
      #pragma unroll
      for (int g=0; g<4; ++g)
        uxr[g] = *(const us4*)&ux[((long long)bg*200 + s+1)*1024 + g*256 + jlane];
      tnx = ts[(long long)bg*200 + s+1];
    }
    // c_s1 pre-act: Wd GEMV over c fragments
    f32x4 ad = bcs;
    #pragma unroll
    for (int kk=0;kk<8;++kk) ad = MFMA(wdA[kk], cfr[kk], ad);
    // gates: ux + Wall GEMV over h fragments
    #pragma unroll
    for (int kk=0;kk<8;++kk)
      #pragma unroll
      for (int g=0; g<4; ++g) ag[g] = MFMA(wfA[g][kk], hfr[kk], ag[g]);
    // elementwise update (fp32 c carried in regs, C-layout)
    f32x4 hn; us4 hp, cp;
    #pragma unroll
    for (int r=0;r<4;++r){
      float cs1 = tanhx(ad[r]);
      float cadj = creg[r] + cs1*(tcur - 1.0f);
      float fg = sigm(ag[0][r]);
      float ig = sigm(ag[1][r]);
      float og = sigm(ag[2][r]);
      float cg = sigm(ag[3][r]);
      float cn = fg*cadj + ig*cg;
      float hv = og*tanhx(cn);
      creg[r]=cn; hn[r]=hv;
      hp[r]=f2b(hv); cp[r]=f2b(cn);
    }
    tcur = tnx;
    // outputs: lstm0 -> E partial (folded attention dot), lstm1 -> out2
    if (lstm==0){
      float e = hn[0]*wav[0] + hn[1]*wav[1] + hn[2]*wav[2] + hn[3]*wav[3];
      e += __shfl_xor(e, 16, 64);
      e += __shfl_xor(e, 32, 64);
      if (l < 16) atomicAdd(&E[(long long)bg*256 + s], e);
    } else {
      *(us4*)&out2[((long long)bg*200 + s)*256 + jlane] = hp;
    }
    // ---- exchange h,c with the 3 sibling j-WGs ----
    if (s < 199){
      const int slot = (s+1)&1;
      const long long base = ((long long)(slot*16+grp)*16 + lb)*512;  // u16 units
      const int fbase = (slot*16+grp)*64;
      u64 h64, c64;
      __builtin_memcpy(&h64,&hp,8); __builtin_memcpy(&c64,&cp,8);
      __hip_atomic_store((u64*)&mpay[base + jlane],       h64, __ATOMIC_RELAXED, __HIP_MEMORY_SCOPE_AGENT);
      __hip_atomic_store((u64*)&mpay[base + 256 + jlane], c64, __ATOMIC_RELAXED, __HIP_MEMORY_SCOPE_AGENT);
      __syncthreads();                 // B1: all waves' stores acked at MALL
      if (tid == 0)
        __hip_atomic_store(&mflg[fbase + jw*16], (unsigned)(s+1), __ATOMIC_RELAXED, __HIP_MEMORY_SCOPE_AGENT);
      // wave-autonomous poll: lanes 0-2 watch the 3 sibling flags
      const unsigned tgt = (unsigned)(s+1);
      for (;;){
        unsigned fv = tgt;
        if (l < 3)
          fv = __hip_atomic_load(&mflg[fbase + sib*16], __ATOMIC_RELAXED, __HIP_MEMORY_SCOPE_AGENT);
        if ((__ballot(fv == tgt) & 7ULL) == 7ULL) break;
        __builtin_amdgcn_s_sleep(1);
      }
      // refill ALL h/c B-fragments straight into registers (own incl.)
      #pragma unroll
      for (int kk=0;kk<8;++kk){
        long long o = base + kk*32 + quad*8;
        u64 hlo = __hip_atomic_load((const u64*)&mpay[o],      __ATOMIC_RELAXED, __HIP_MEMORY_SCOPE_AGENT);
        u64 hhi = __hip_atomic_load((const u64*)&mpay[o+4],    __ATOMIC_RELAXED, __HIP_MEMORY_SCOPE_AGENT);
        u64 clo = __hip_atomic_load((const u64*)&mpay[o+256],  __ATOMIC_RELAXED, __HIP_MEMORY_SCOPE_AGENT);
        u64 chi = __hip_atomic_load((const u64*)&mpay[o+260],  __ATOMIC_RELAXED, __HIP_MEMORY_SCOPE_AGENT);
        union { u64 q[2]; bf16x8 v; } th, tc;
        th.q[0]=hlo; th.q[1]=hhi; tc.q[0]=clo; tc.q[1]=chi;
        hfr[kk]=th.v; cfr[kk]=tc.v;
      }
    }
  }
}

// ---------------- softmax over precomputed E -> alpha ----------------
__global__ __launch_bounds__(256) void k_attn(const float* __restrict__ E, float* __restrict__ alpha){
  __shared__ float buf[256];
  int b = blockIdx.x, tid = threadIdx.x;
  float Ev = (tid < 200) ? E[(long long)b*256 + tid] : -1e30f;
  buf[tid]=Ev; __syncthreads();
  for (int st=128; st>0; st>>=1){ if (tid<st) buf[tid]=fmaxf(buf[tid],buf[tid+st]); __syncthreads(); }
  float mx = buf[0]; __syncthreads();
  float e = (tid<200)? __expf(Ev-mx) : 0.f;
  buf[tid]=e; __syncthreads();
  for (int st=128; st>0; st>>=1){ if (tid<st) buf[tid]+=buf[tid+st]; __syncthreads(); }
  float sm = buf[0];
  if (tid<200) alpha[(long long)b*200+tid] = e/sm;
}

// ---------------- out = ctx @ Wout^T ----------------
__global__ __launch_bounds__(128) void k_out(const float* __restrict__ ctx, const float* __restrict__ Wout,
                                             float* __restrict__ out){
  __shared__ float cs[256];
  int b = blockIdx.x, t = threadIdx.x;
  cs[t] = ctx[b*256+t]; cs[t+128] = ctx[b*256+t+128];
  __syncthreads();
  const float* wr = Wout + (long long)t*256;
  float a0=0,a1=0,a2=0,a3=0;
  for (int j=0;j<256;j+=4){
    f32x4 v = *(const f32x4*)&wr[j];
    a0+=v[0]*cs[j]; a1+=v[1]*cs[j+1]; a2+=v[2]*cs[j+2]; a3+=v[3]*cs[j+3];
  }
  out[(long long)b*128 + t] = (a0+a1)+(a2+a3);
}

extern "C" void kernel_launch(void* const* d_in, const int* in_sizes, int n_in,
                              void* d_out, int out_size, void* d_ws, size_t ws_size,
                              hipStream_t stream)
{
  (void)in_sizes; (void)n_in; (void)out_size; (void)ws_size;
  const float* inputs = (const float*)d_in[0];
  const float* tstamp = (const float*)d_in[1];
  const float* emb    = (const float*)d_in[2];
  const float* Wall1w = (const float*)d_in[3];
  const float* Wall1b = (const float*)d_in[4];
  const float* Uall1w = (const float*)d_in[5];
  const float* Uall1b = (const float*)d_in[6];
  const float* Wd1w   = (const float*)d_in[7];
  const float* Wd1b   = (const float*)d_in[8];
  const float* Wall2w = (const float*)d_in[9];
  const float* Wall2b = (const float*)d_in[10];
  const float* Uall2w = (const float*)d_in[11];
  const float* Uall2b = (const float*)d_in[12];
  const float* Wd2w   = (const float*)d_in[13];
  const float* Wd2b   = (const float*)d_in[14];
  const float* wa     = (const float*)d_in[15];
  const float* Wbw    = (const float*)d_in[16];
  const float* Woutw  = (const float*)d_in[17];
  const float* h01    = (const float*)d_in[18];
  const float* c01    = (const float*)d_in[19];
  const float* h02    = (const float*)d_in[20];
  const float* c02    = (const float*)d_in[21];

  char* ws = (char*)d_ws;
  u16*   ux1   = (u16*)  (ws + 0);              // 52428800
  u16*   ux2   = (u16*)  (ws + 52428800LL);
  float* embF  = (float*)(ws + 104857600LL);    // 26214400
  u16*   embB  = (u16*)  (ws + 131072000LL);    // 13107200
  char*  scr   =          ws + 144179200LL;     // 72089600 region (A0 overlay)
  u16*   A0    = (u16*)scr;                     // 72089600 (dead after embed GEMM)
  u16*   out2  = (u16*)  (scr + 0);             // 13107200
  float* E     = (float*)(scr + 13107200LL);    // 131072 (stride-256 padded)
  float* ctx   = (float*)(scr + 13238272LL);    // 131072
  float* alpha = (float*)(scr + 13369344LL);    // 102400
  u16*   mpay  = (u16*)  (scr + 13471744LL);    // 524288
  unsigned* mflg=(unsigned*)(scr + 13996032LL); // 8192
  u16* embT    = (u16*)(ws + 216268800LL);      // 720896
  u16* Wall1B  = (u16*)(ws + 216989696LL);      // 524288
  u16* Wall2B  = (u16*)(ws + 217513984LL);
  u16* Uall1B  = (u16*)(ws + 218038272LL);
  u16* Uall2B  = (u16*)(ws + 218562560LL);
  u16* Wd1B    = (u16*)(ws + 219086848LL);      // 131072
  u16* Wd2B    = (u16*)(ws + 219217920LL);
  u16* WbB     = (u16*)(ws + 219348992LL);
  // total ws: ~219.5 MB

  // 1) all conversions (inputs, emb^T, 7 weights) in one launch
  k_prep<<<37824, 256, 0, stream>>>(inputs, A0, emb, embT,
                                    Wall1w, Wall2w, Uall1w, Uall2w, Wd1w, Wd2w, Wbw,
                                    Wall1B, Wall2B, Uall1B, Uall2B, Wd1B, Wd2B, WbB);
  // 2) embedded = inputs @ emb  (fp32 + bf16 copies)
  k_gemm<1><<<dim3(200,2), 256, 0, stream>>>(A0, embT, 256, 1408, embF, embB,
                                             nullptr, nullptr, nullptr, nullptr,
                                             nullptr, nullptr, nullptr, nullptr);
  // 3) ux1,ux2 = bf16( embedded @ Uall{1,2}^T + (Uall_b + Wall_b) ), one launch
  k_gemm<6><<<dim3(200,16), 256, 0, stream>>>(embB, Uall1B, 1024, 256, nullptr, ux1,
                                              Uall1b, Wall1b,
                                              Uall2B, ux2, Uall2b, Wall2b,
                                              nullptr, nullptr);
  // 4) zero E + ctx (atomic accumulation targets; after A0 is dead)
  k_init<<<256, 256, 0, stream>>>(E, ctx);
  // 5) both TimeLSTM scans (64 persistent WGs, register-resident everything)
  k_scan<<<64, 256, 0, stream>>>(Wall1B, Wd1B, Wd1b, ux1, h01, c01,
                                 Wall2B, Wd2B, Wd2b, ux2, h02, c02,
                                 tstamp, wa, E, out2, mpay, mflg);
  // 6) alpha = softmax(E)
  k_attn<<<128, 256, 0, stream>>>(E, alpha);
  // 7) ctx += sum_s emb * tanh(out2 @ Wb^T) * alpha  (fused, no P buffer)
  k_gemm<5><<<dim3(200,2), 256, 0, stream>>>(out2, WbB, 256, 256, ctx, nullptr,
                                             nullptr, nullptr, nullptr, nullptr,
                                             nullptr, nullptr, embF, alpha);
  // 8) out = ctx @ Wout^T
  k_out<<<128, 128, 0, stream>>>(ctx, Woutw, (float*)d_out);
}

// Round 7
// 1288.778 us; speedup vs baseline: 1.4172x; 1.2598x over previous
//
#include <hip/hip_runtime.h>

typedef unsigned short u16;
typedef unsigned long long u64;
typedef __attribute__((ext_vector_type(8))) short bf16x8;
typedef __attribute__((ext_vector_type(4))) float f32x4;
typedef __attribute__((ext_vector_type(4))) unsigned short us4;

#define MFMA(a,b,c) __builtin_amdgcn_mfma_f32_16x16x32_bf16((a),(b),(c),0,0,0)
#define KEEP(x) asm volatile("" : "+v"(x))

// B=128, SEQ=200, VOCAB=1400 (pad 1408), D=H=256, 4H=1024, NCLS=128, M=B*SEQ=25600

static __device__ __forceinline__ u16 f2b(float f){
  unsigned u = __float_as_uint(f);
  u += 0x7fffu + ((u >> 16) & 1u);          // RNE fp32 -> bf16
  return (u16)(u >> 16);
}
static __device__ __forceinline__ float b2f(u16 v){
  return __uint_as_float(((unsigned)v) << 16);
}
static __device__ __forceinline__ float sigm(float x){ return 1.0f/(1.0f+__expf(-x)); }
static __device__ __forceinline__ float tanhx(float x){
  x = fminf(fmaxf(x, -15.f), 15.f);
  float e = __expf(-2.f*x);
  return (1.f - e)/(1.f + e);
}
static __device__ __forceinline__ void gl16(const void* g, void* l){
  __builtin_amdgcn_global_load_lds((const __attribute__((address_space(1))) void*)g,
                                   (__attribute__((address_space(3))) void*)l, 16, 0, 0);
}

// ---------------- fused prep: inputs cvt + emb transpose-cvt + weights ----
__global__ __launch_bounds__(256) void k_prep(
  const float* __restrict__ in0, u16* __restrict__ A0,
  const float* __restrict__ emb, u16* __restrict__ embT,
  const float* __restrict__ s0, const float* __restrict__ s1, const float* __restrict__ s2,
  const float* __restrict__ s3, const float* __restrict__ s4, const float* __restrict__ s5,
  const float* __restrict__ s6,
  u16* __restrict__ d0, u16* __restrict__ d1, u16* __restrict__ d2, u16* __restrict__ d3,
  u16* __restrict__ d4, u16* __restrict__ d5, u16* __restrict__ d6)
{
  int bx = blockIdx.x, tid = threadIdx.x;
  if (bx < 35200){                     // inputs [25600 x 1400] -> bf16 padded 1408
    long long i4 = (long long)bx*256 + tid;      // < 9011200 exactly
    long long o = i4*4;
    int r = (int)(o / 1408);
    int c = (int)(o % 1408);
    us4 d;
    if (c + 4 <= 1400){
      f32x4 v = *(const f32x4*)&in0[(long long)r*1400 + c];
      d[0]=f2b(v[0]); d[1]=f2b(v[1]); d[2]=f2b(v[2]); d[3]=f2b(v[3]);
    } else {
      for (int k=0;k<4;k++){ int cc=c+k; d[k] = (cc<1400)? f2b(in0[(long long)r*1400+cc]) : (u16)0; }
    }
    *(us4*)&A0[(long long)r*1408 + c] = d;
  } else if (bx < 36608){              // emb [1400x256] -> embT [256x1408] bf16
    int idx = (bx-35200)*256 + tid;    // < 360448 exactly
    int n = idx / 1408, k = idx % 1408;
    embT[idx] = (k < 1400) ? f2b(emb[(long long)k*256 + n]) : (u16)0;
  } else {                             // 7 weight arrays fp32 -> bf16
    long long q = (long long)(bx-36608)*256 + tid;   // < 311296 exactly
    const float* src; u16* dst; long long rel;
    if      (q < 65536)  { src=s0; dst=d0; rel=q; }
    else if (q < 131072) { src=s1; dst=d1; rel=q-65536; }
    else if (q < 196608) { src=s2; dst=d2; rel=q-131072; }
    else if (q < 262144) { src=s3; dst=d3; rel=q-196608; }
    else if (q < 278528) { src=s4; dst=d4; rel=q-262144; }
    else if (q < 294912) { src=s5; dst=d5; rel=q-278528; }
    else                 { src=s6; dst=d6; rel=q-294912; }
    long long o = rel*4;
    f32x4 v = *(const f32x4*)&src[o];
    us4 d; d[0]=f2b(v[0]); d[1]=f2b(v[1]); d[2]=f2b(v[2]); d[3]=f2b(v[3]);
    *(us4*)&dst[o] = d;
  }
}

// ---------------- init: zero E + ctx ----------------
__global__ __launch_bounds__(256) void k_init(float* __restrict__ E, float* __restrict__ ctx){
  int i = blockIdx.x*256 + threadIdx.x;     // 256*256 = 65536 exactly
  if (i < 32768) E[i] = 0.f;
  else ctx[i-32768] = 0.f;
}

// ---------------- bf16 MFMA GEMM: C[M,N] = A[M,K] * Bt[N,K]^T -------------
// EPI 1: write fp32 + bf16 copies
// EPI 6: dual bf16 ux output, +bias pair (blockIdx.y>=8 -> second set)
// EPI 5: ctx[b,col] += emb[row,col]*tanh(acc)*alpha[row]  (LDS + global atomics)
template<int EPI>
__global__ __launch_bounds__(256) void k_gemm(const u16* __restrict__ A, const u16* __restrict__ Bt,
    int N, int K,
    float* __restrict__ Cf, u16* __restrict__ Cb,
    const float* __restrict__ bias1, const float* __restrict__ bias2,
    const u16* __restrict__ Bt2, u16* __restrict__ Cb2,
    const float* __restrict__ bias3, const float* __restrict__ bias4,
    const float* __restrict__ emb, const float* __restrict__ alpha)
{
  __shared__ __align__(16) u16 As[128*64];
  __shared__ __align__(16) u16 Bs[128*64];
  __shared__ float red[2][128];
  const int tid = threadIdx.x;
  const int l = tid & 63, w = tid >> 6;
  const int quad = l >> 4, lb = l & 15;
  const int wr = w >> 1, wc = w & 1;
  const long long m0 = (long long)blockIdx.x * 128;
  int n0 = blockIdx.y * 128;
  if (EPI==6 && blockIdx.y >= 8){
    Bt = Bt2; Cb = Cb2; bias1 = bias3; bias2 = bias4; n0 = (blockIdx.y-8)*128;
  }

  f32x4 acc[4][4];
  #pragma unroll
  for (int i=0;i<4;i++)
    #pragma unroll
    for (int j=0;j<4;j++) acc[i][j] = (f32x4){0.f,0.f,0.f,0.f};

  for (int kk = 0; kk < K; kk += 64){
    #pragma unroll
    for (int it=0; it<4; ++it){      // 128x64 bf16 tile, XOR-swizzled 16B slots
      int slot = it*256 + tid;
      int m = slot >> 3;
      int q = (slot & 7) ^ (m & 7);
      gl16(A + (m0+m)*K + kk + q*8, &As[slot*8]);
    }
    #pragma unroll
    for (int it=0; it<4; ++it){
      int slot = it*256 + tid;
      int m = slot >> 3;
      int q = (slot & 7) ^ (m & 7);
      gl16(Bt + (long long)(n0+m)*K + kk + q*8, &Bs[slot*8]);
    }
    __syncthreads();
    #pragma unroll
    for (int ks=0; ks<2; ++ks){
      int kq = quad + ks*4;
      bf16x8 af[4], bfr[4];
      #pragma unroll
      for (int i=0;i<4;i++){ int m = wr*64 + i*16 + lb; af[i]  = *(const bf16x8*)&As[m*64 + ((kq ^ (m&7))*8)]; }
      #pragma unroll
      for (int j=0;j<4;j++){ int n = wc*64 + j*16 + lb; bfr[j] = *(const bf16x8*)&Bs[n*64 + ((kq ^ (n&7))*8)]; }
      #pragma unroll
      for (int i=0;i<4;i++)
        #pragma unroll
        for (int j=0;j<4;j++)
          acc[i][j] = MFMA(af[i], bfr[j], acc[i][j]);
    }
    __syncthreads();
  }

  if (EPI==5){
    const int b0 = (int)(m0 / 200);
    red[tid>>7][tid&127] = 0.f;
    __syncthreads();
    #pragma unroll
    for (int i=0;i<4;i++){
      #pragma unroll
      for (int j=0;j<4;j++){
        int col = wc*64 + j*16 + lb;          // 0..127 within n0 tile
        #pragma unroll
        for (int r=0;r<4;r++){
          long long row = m0 + wr*64 + i*16 + quad*4 + r;
          long long o = row*N + n0 + col;
          float v = emb[o] * tanhx(acc[i][j][r]) * alpha[row];
          atomicAdd(&red[(int)(row/200) - b0][col], v);
        }
      }
    }
    __syncthreads();
    int bl = tid >> 7, col = tid & 127;       // 256 threads cover [2][128]
    int bb = b0 + bl;
    if (bb < 128) atomicAdd(&Cf[bb*256 + n0 + col], red[bl][col]);
    return;
  }

  #pragma unroll
  for (int i=0;i<4;i++){
    #pragma unroll
    for (int j=0;j<4;j++){
      int col = n0 + wc*64 + j*16 + lb;
      #pragma unroll
      for (int r=0;r<4;r++){
        long long row = m0 + wr*64 + i*16 + quad*4 + r;
        long long o = row*N + col;
        float v = acc[i][j][r];
        if (EPI==1){ Cf[o]=v; Cb[o]=f2b(v); }
        else if (EPI==6){ Cb[o] = f2b(v + bias1[col] + bias2[col]); }
      }
    }
  }
}

// ---------------- persistent TimeLSTM scan (tagged-payload exchange) ------
// 64 WGs: bi>>5 = lstm, (bi>>2)&7 = batch chunk of 16, bi&3 = j-chunk of 64.
// Exchange: each compute lane packs h[4]/c[4] into THREE u64 words, each
// carrying 3 data u16 + a 16-bit step tag (tag=s+1; 0xAAAA poison and stale
// tag s-1 never match). Readers poll the DATA WORDS directly at the MALL:
// one RT delivers validity + payload (no drain, no flag, no separate refill).
// Slot reuse (2 slots) safe: reading tag-t is a prerequisite of publishing
// t+1, so overwrite at t+2 follows all tag-t reads. LDS staging (R3-style)
// does the [b][j] -> B-fragment transform. Barriers are RAW s_barrier (B1,
// LDS WAR) and lgkmcnt+s_barrier (B2, LDS visibility) -- no vmcnt(0) drain
// on the critical path.
__global__ __launch_bounds__(256,1) void k_scan(
  const u16* __restrict__ Wall1, const u16* __restrict__ Wd1, const float* __restrict__ Wd1b,
  const u16* __restrict__ ux1, const float* __restrict__ h01, const float* __restrict__ c01,
  const u16* __restrict__ Wall2, const u16* __restrict__ Wd2, const float* __restrict__ Wd2b,
  const u16* __restrict__ ux2, const float* __restrict__ h02, const float* __restrict__ c02,
  const float* __restrict__ ts, const float* __restrict__ wa,
  float* __restrict__ E, u16* __restrict__ out2,
  u64* __restrict__ pay)
{
  __shared__ __align__(16) u16 hb[16][264];
  __shared__ __align__(16) u16 cb[16][264];
  const int bi = blockIdx.x;
  const int lstm = bi >> 5;
  const int bc   = (bi >> 2) & 7;
  const int jw   = bi & 3;
  const int grp  = bi >> 2;            // 0..15, distinct per (lstm,bc)
  const u16* Wall  = lstm ? Wall2 : Wall1;
  const u16* Wd    = lstm ? Wd2   : Wd1;
  const float* Wdb = lstm ? Wd2b  : Wd1b;
  const u16* ux    = lstm ? ux2   : ux1;
  const float* h0  = lstm ? h02   : h01;
  const float* c0  = lstm ? c02   : c01;

  const int tid = threadIdx.x;
  const int l = tid & 63, w = tid >> 6;
  const int quad = l >> 4, lb = l & 15;
  const int bg = bc*16 + lb;            // lane's global batch
  const int jwave = jw*64 + w*16;       // wave's 16 output rows (per gate)
  const int jlane = jwave + quad*4;     // lane's 4 j rows (C-layout)
  const int bb = tid >> 4, jj = tid & 15;   // refill role: batch bb, j-block jj*16
  const bool sibR = (jj >> 2) != jw;        // refill from sibling WG?

  // ---- one-time: weight fragments into registers (A-frag: m=lb, k=quad*8+i)
  bf16x8 wfA[4][8], wdA[8];
  #pragma unroll
  for (int g=0; g<4; ++g)
    #pragma unroll
    for (int kk=0; kk<8; ++kk){
      wfA[g][kk] = *(const bf16x8*)&Wall[(long long)(g*256 + jwave + lb)*256 + kk*32 + quad*8];
      KEEP(wfA[g][kk]);
    }
  #pragma unroll
  for (int kk=0; kk<8; ++kk){
    wdA[kk] = *(const bf16x8*)&Wd[(long long)(jwave + lb)*256 + kk*32 + quad*8];
    KEEP(wdA[kk]);
  }

  f32x4 bcs  = *(const f32x4*)&Wdb[jlane];
  f32x4 wav  = *(const f32x4*)&wa[jlane];
  f32x4 creg = *(const f32x4*)&c0[(long long)bg*256 + jlane];

  // ---- init LDS h/c (full 256 j for our 16 batches), bf16
  {
    int j0 = jj*16;
    #pragma unroll
    for (int kq=0; kq<4; ++kq){
      f32x4 hv = *(const f32x4*)&h0[(long long)(bc*16+bb)*256 + j0 + kq*4];
      f32x4 cv = *(const f32x4*)&c0[(long long)(bc*16+bb)*256 + j0 + kq*4];
      us4 hp0, cp0;
      #pragma unroll
      for (int r=0;r<4;++r){ hp0[r]=f2b(hv[r]); cp0[r]=f2b(cv[r]); }
      *(us4*)&hb[bb][j0+kq*4] = hp0;
      *(us4*)&cb[bb][j0+kq*4] = cp0;
    }
  }
  __syncthreads();

  us4 uxr[4];
  #pragma unroll
  for (int g=0; g<4; ++g)
    uxr[g] = *(const us4*)&ux[(long long)bg*200*1024 + g*256 + jlane];
  float tcur = ts[(long long)bg*200];

  for (int s=0; s<200; ++s){
    // consume ux(s), then prefetch ux(s+1)/ts(s+1) early (hides HBM latency)
    f32x4 ag[4];
    #pragma unroll
    for (int g=0; g<4; ++g)
      #pragma unroll
      for (int r=0; r<4; ++r) ag[g][r] = b2f(uxr[g][r]);
    float tnx = 0.f;
    if (s < 199){
      #pragma unroll
      for (int g=0; g<4; ++g)
        uxr[g] = *(const us4*)&ux[((long long)bg*200 + s+1)*1024 + g*256 + jlane];
      tnx = ts[(long long)bg*200 + s+1];
    }
    // c_s1 pre-act: Wd GEMV over cb
    f32x4 ad = bcs;
    #pragma unroll
    for (int kk=0;kk<8;++kk){
      bf16x8 cf = *(const bf16x8*)&cb[lb][kk*32 + quad*8];
      ad = MFMA(wdA[kk], cf, ad);
    }
    // gates: ux + Wall GEMV over hb
    #pragma unroll
    for (int kk=0;kk<8;++kk){
      bf16x8 hf = *(const bf16x8*)&hb[lb][kk*32 + quad*8];
      #pragma unroll
      for (int g=0; g<4; ++g) ag[g] = MFMA(wfA[g][kk], hf, ag[g]);
    }
    // elementwise update (fp32 c carried in regs, C-layout)
    f32x4 hn; us4 hp, cp;
    #pragma unroll
    for (int r=0;r<4;++r){
      float cs1 = tanhx(ad[r]);
      float cadj = creg[r] + cs1*(tcur - 1.0f);
      float fg = sigm(ag[0][r]);
      float ig = sigm(ag[1][r]);
      float og = sigm(ag[2][r]);
      float cg = sigm(ag[3][r]);
      float cn = fg*cadj + ig*cg;
      float hv = og*tanhx(cn);
      creg[r]=cn; hn[r]=hv;
      hp[r]=f2b(hv); cp[r]=f2b(cn);
    }
    tcur = tnx;
    // ---- publish FIRST (tagged payload; fire-and-forget, off critical path)
    if (s < 199){
      const u64 tag = (u64)(s+1);
      const int slot = (s+1)&1;
      long long pw = ((((long long)(slot*16+grp))*16 + lb)*64 + (jlane>>2))*3;
      u64 w0 = (u64)hp[0] | ((u64)hp[1]<<16) | ((u64)hp[2]<<32) | (tag<<48);
      u64 w1 = (u64)hp[3] | ((u64)cp[0]<<16) | ((u64)cp[1]<<32) | (tag<<48);
      u64 w2 = (u64)cp[2] | ((u64)cp[3]<<16) | (tag<<48);
      __hip_atomic_store(&pay[pw],   w0, __ATOMIC_RELAXED, __HIP_MEMORY_SCOPE_AGENT);
      __hip_atomic_store(&pay[pw+1], w1, __ATOMIC_RELAXED, __HIP_MEMORY_SCOPE_AGENT);
      __hip_atomic_store(&pay[pw+2], w2, __ATOMIC_RELAXED, __HIP_MEMORY_SCOPE_AGENT);
    }
    // outputs: lstm0 -> E partial (folded attention dot), lstm1 -> out2
    if (lstm==0){
      float e = hn[0]*wav[0] + hn[1]*wav[1] + hn[2]*wav[2] + hn[3]*wav[3];
      e += __shfl_xor(e, 16, 64);
      e += __shfl_xor(e, 32, 64);
      if (l < 16) atomicAdd(&E[(long long)bg*256 + s], e);
    } else {
      *(us4*)&out2[((long long)bg*200 + s)*256 + jlane] = hp;
    }
    if (s < 199){
      const u64 tag = (u64)(s+1);
      const int slot = (s+1)&1;
      // B1: raw barrier -- all waves' step-s LDS reads are consumed (data
      // dependency), so LDS overwrite is safe; publish ack NOT waited.
      asm volatile("s_barrier" ::: "memory");
      // own chunk: registers -> LDS
      *(us4*)&hb[lb][jlane] = hp;
      *(us4*)&cb[lb][jlane] = cp;
      // sibling chunks: poll tagged words at MALL, unpack -> LDS
      if (sibR){
        long long rb = (((long long)(slot*16+grp))*16 + bb)*192 + (long long)jj*12;
        u64 W[12];
        for (;;){
          #pragma unroll
          for (int i=0;i<12;++i)
            W[i] = __hip_atomic_load(&pay[rb+i], __ATOMIC_RELAXED, __HIP_MEMORY_SCOPE_AGENT);
          bool ok = true;
          #pragma unroll
          for (int i=0;i<12;++i) ok &= ((W[i]>>48) == tag);
          if (ok) break;
          __builtin_amdgcn_s_sleep(1);
        }
        #pragma unroll
        for (int i=0;i<4;++i){
          u64 w0=W[i*3], w1=W[i*3+1], w2=W[i*3+2];
          us4 hv, cv;
          hv[0]=(u16)w0; hv[1]=(u16)(w0>>16); hv[2]=(u16)(w0>>32); hv[3]=(u16)w1;
          cv[0]=(u16)(w1>>16); cv[1]=(u16)(w1>>32); cv[2]=(u16)w2; cv[3]=(u16)(w2>>16);
          *(us4*)&hb[bb][jj*16+i*4] = hv;
          *(us4*)&cb[bb][jj*16+i*4] = cv;
        }
      }
      // B2: LDS writes visible to all waves
      asm volatile("s_waitcnt lgkmcnt(0)\n\ts_barrier" ::: "memory");
    }
  }
}

// ---------------- softmax over precomputed E -> alpha ----------------
__global__ __launch_bounds__(256) void k_attn(const float* __restrict__ E, float* __restrict__ alpha){
  __shared__ float buf[256];
  int b = blockIdx.x, tid = threadIdx.x;
  float Ev = (tid < 200) ? E[(long long)b*256 + tid] : -1e30f;
  buf[tid]=Ev; __syncthreads();
  for (int st=128; st>0; st>>=1){ if (tid<st) buf[tid]=fmaxf(buf[tid],buf[tid+st]); __syncthreads(); }
  float mx = buf[0]; __syncthreads();
  float e = (tid<200)? __expf(Ev-mx) : 0.f;
  buf[tid]=e; __syncthreads();
  for (int st=128; st>0; st>>=1){ if (tid<st) buf[tid]+=buf[tid+st]; __syncthreads(); }
  float sm = buf[0];
  if (tid<200) alpha[(long long)b*200+tid] = e/sm;
}

// ---------------- out = ctx @ Wout^T ----------------
__global__ __launch_bounds__(128) void k_out(const float* __restrict__ ctx, const float* __restrict__ Wout,
                                             float* __restrict__ out){
  __shared__ float cs[256];
  int b = blockIdx.x, t = threadIdx.x;
  cs[t] = ctx[b*256+t]; cs[t+128] = ctx[b*256+t+128];
  __syncthreads();
  const float* wr = Wout + (long long)t*256;
  float a0=0,a1=0,a2=0,a3=0;
  for (int j=0;j<256;j+=4){
    f32x4 v = *(const f32x4*)&wr[j];
    a0+=v[0]*cs[j]; a1+=v[1]*cs[j+1]; a2+=v[2]*cs[j+2]; a3+=v[3]*cs[j+3];
  }
  out[(long long)b*128 + t] = (a0+a1)+(a2+a3);
}

extern "C" void kernel_launch(void* const* d_in, const int* in_sizes, int n_in,
                              void* d_out, int out_size, void* d_ws, size_t ws_size,
                              hipStream_t stream)
{
  (void)in_sizes; (void)n_in; (void)out_size; (void)ws_size;
  const float* inputs = (const float*)d_in[0];
  const float* tstamp = (const float*)d_in[1];
  const float* emb    = (const float*)d_in[2];
  const float* Wall1w = (const float*)d_in[3];
  const float* Wall1b = (const float*)d_in[4];
  const float* Uall1w = (const float*)d_in[5];
  const float* Uall1b = (const float*)d_in[6];
  const float* Wd1w   = (const float*)d_in[7];
  const float* Wd1b   = (const float*)d_in[8];
  const float* Wall2w = (const float*)d_in[9];
  const float* Wall2b = (const float*)d_in[10];
  const float* Uall2w = (const float*)d_in[11];
  const float* Uall2b = (const float*)d_in[12];
  const float* Wd2w   = (const float*)d_in[13];
  const float* Wd2b   = (const float*)d_in[14];
  const float* wa     = (const float*)d_in[15];
  const float* Wbw    = (const float*)d_in[16];
  const float* Woutw  = (const float*)d_in[17];
  const float* h01    = (const float*)d_in[18];
  const float* c01    = (const float*)d_in[19];
  const float* h02    = (const float*)d_in[20];
  const float* c02    = (const float*)d_in[21];

  char* ws = (char*)d_ws;
  u16*   ux1   = (u16*)  (ws + 0);              // 52428800
  u16*   ux2   = (u16*)  (ws + 52428800LL);
  float* embF  = (float*)(ws + 104857600LL);    // 26214400
  u16*   embB  = (u16*)  (ws + 131072000LL);    // 13107200
  char*  scr   =          ws + 144179200LL;     // 72089600 region (A0 overlay)
  u16*   A0    = (u16*)scr;                     // 72089600 (dead after embed GEMM)
  u16*   out2  = (u16*)  (scr + 0);             // 13107200
  float* E     = (float*)(scr + 13107200LL);    // 131072 (stride-256 padded)
  float* ctx   = (float*)(scr + 13238272LL);    // 131072
  float* alpha = (float*)(scr + 13369344LL);    // 102400
  u64*   pay   = (u64*)  (scr + 13471744LL);    // 786432 (2 slots x 16 grp x 3072 u64)
  u16* embT    = (u16*)(ws + 216268800LL);      // 720896
  u16* Wall1B  = (u16*)(ws + 216989696LL);      // 524288
  u16* Wall2B  = (u16*)(ws + 217513984LL);
  u16* Uall1B  = (u16*)(ws + 218038272LL);
  u16* Uall2B  = (u16*)(ws + 218562560LL);
  u16* Wd1B    = (u16*)(ws + 219086848LL);      // 131072
  u16* Wd2B    = (u16*)(ws + 219217920LL);
  u16* WbB     = (u16*)(ws + 219348992LL);
  // total ws: ~219.5 MB

  // 1) all conversions (inputs, emb^T, 7 weights) in one launch
  k_prep<<<37824, 256, 0, stream>>>(inputs, A0, emb, embT,
                                    Wall1w, Wall2w, Uall1w, Uall2w, Wd1w, Wd2w, Wbw,
                                    Wall1B, Wall2B, Uall1B, Uall2B, Wd1B, Wd2B, WbB);
  // 2) embedded = inputs @ emb  (fp32 + bf16 copies)
  k_gemm<1><<<dim3(200,2), 256, 0, stream>>>(A0, embT, 256, 1408, embF, embB,
                                             nullptr, nullptr, nullptr, nullptr,
                                             nullptr, nullptr, nullptr, nullptr);
  // 3) ux1,ux2 = bf16( embedded @ Uall{1,2}^T + (Uall_b + Wall_b) ), one launch
  k_gemm<6><<<dim3(200,16), 256, 0, stream>>>(embB, Uall1B, 1024, 256, nullptr, ux1,
                                              Uall1b, Wall1b,
                                              Uall2B, ux2, Uall2b, Wall2b,
                                              nullptr, nullptr);
  // 4) zero E + ctx (atomic accumulation targets; after A0 is dead)
  k_init<<<256, 256, 0, stream>>>(E, ctx);
  // 5) both TimeLSTM scans (64 persistent WGs, tagged-payload exchange)
  k_scan<<<64, 256, 0, stream>>>(Wall1B, Wd1B, Wd1b, ux1, h01, c01,
                                 Wall2B, Wd2B, Wd2b, ux2, h02, c02,
                                 tstamp, wa, E, out2, pay);
  // 6) alpha = softmax(E)
  k_attn<<<128, 256, 0, stream>>>(E, alpha);
  // 7) ctx += sum_s emb * tanh(out2 @ Wb^T) * alpha  (fused, no P buffer)
  k_gemm<5><<<dim3(200,2), 256, 0, stream>>>(out2, WbB, 256, 256, ctx, nullptr,
                                             nullptr, nullptr, nullptr, nullptr,
                                             nullptr, nullptr, embF, alpha);
  // 8) out = ctx @ Wout^T
  k_out<<<128, 128, 0, stream>>>(ctx, Woutw, (float*)d_out);
}